// Round 8
// baseline (623.379 us; speedup 1.0000x reference)
//
#include <hip/hip_runtime.h>
#include <hip/hip_bf16.h>
#include <math.h>

#define NN 50000
#define NE 320000
#define SCAN_NBLK ((NN + 255) / 256)   // 196

typedef __attribute__((ext_vector_type(8))) short bf16x8;   // 8 bf16 (4 VGPRs)
typedef __attribute__((ext_vector_type(4))) float floatx4;  // MFMA C/D
typedef __attribute__((ext_vector_type(4))) unsigned int uintx4;  // true vector type
                                                                  // (nontemporal builtin needs it)

static __device__ __forceinline__ unsigned pack2bf(float a, float b) {
    __hip_bfloat162 h = __float22bfloat162_rn(make_float2(a, b));
    return *reinterpret_cast<unsigned*>(&h);
}
static __device__ __forceinline__ unsigned short f2bf(float x) {
    __hip_bfloat16 h = __float2bfloat16(x);
    return *reinterpret_cast<unsigned short*>(&h);
}
static __device__ __forceinline__ float bf2f(unsigned short u) {
    return __uint_as_float(((unsigned)u) << 16);
}
// unpack a uint holding two bf16: low short -> float, high short -> float
static __device__ __forceinline__ float bflo(unsigned u) {
    return __uint_as_float(u << 16);
}
static __device__ __forceinline__ float bfhi(unsigned u) {
    return __uint_as_float(u & 0xffff0000u);
}
// async global->LDS, 16B per lane; lds dest = wave-uniform base + lane*16
static __device__ __forceinline__ void gload_lds16(const void* g, void* l) {
    __builtin_amdgcn_global_load_lds(
        (const __attribute__((address_space(1))) void*)g,
        (__attribute__((address_space(3))) void*)l, 16, 0, 0);
}

// ---------------------------------------------------------------------------
// fp32 -> bf16 streaming convert, 8 elems/thread. n8 = n/8.
// ---------------------------------------------------------------------------
__global__ __launch_bounds__(256)
void cvt_bf16_kernel(const float* __restrict__ in,
                     unsigned short* __restrict__ out, int n8)
{
    int t = blockIdx.x * 256 + threadIdx.x;
    if (t >= n8) return;
    const float4* p = (const float4*)in + (size_t)t * 2;
    float4 a = p[0], b = p[1];
    uint4 u;
    u.x = pack2bf(a.x, a.y); u.y = pack2bf(a.z, a.w);
    u.z = pack2bf(b.x, b.y); u.w = pack2bf(b.z, b.w);
    ((uint4*)out)[t] = u;
}

// ---------------------------------------------------------------------------
// Node projections, pure-bf16 MFMA GEMM with global_load_lds staging.
// C = Xb @ Wb^T (+bias). blockIdx.y = ct: mat = ct>>1, half = ct&1.
// 128x128 tile, BK=64, 4 waves 2x2, 4x4 16x16x32 frags, 2 k-steps per stage.
// ---------------------------------------------------------------------------
__global__ __launch_bounds__(256)
void node_gemm_kernel(const unsigned short* __restrict__ Xb,
                      const unsigned short* __restrict__ Wqb,
                      const unsigned short* __restrict__ Wkb,
                      const unsigned short* __restrict__ Wvb,
                      const unsigned short* __restrict__ Wsb,
                      const float* __restrict__ bq, const float* __restrict__ bk,
                      const float* __restrict__ bv, const float* __restrict__ bs,
                      unsigned short* __restrict__ qb,
                      unsigned short* __restrict__ kb,
                      unsigned short* __restrict__ vb,
                      float* __restrict__ outS)
{
    const int m0  = blockIdx.x * 128;
    const int ct  = blockIdx.y;
    const int mat = ct >> 1, half = ct & 1;
    const int colbase = half * 128;

    const unsigned short* __restrict__ W;
    const float* __restrict__ bias;
    switch (mat) {
        case 0:  W = Wqb; bias = bq; break;
        case 1:  W = Wkb; bias = bk; break;
        case 2:  W = Wvb; bias = bv; break;
        default: W = Wsb; bias = bs; break;
    }
    W += (size_t)colbase * 256;

    __shared__ __align__(16) unsigned char smem[32768];
    short* sA = (short*)smem;             // [128][64]
    short* sB = (short*)(smem + 16384);   // [128][64]

    const int tid  = threadIdx.x;
    const int lane = tid & 63;
    const int wave = tid >> 6;
    const int wm   = (wave & 1) * 64;
    const int wn   = (wave >> 1) * 64;
    const int lr   = lane & 15;
    const int lq   = lane >> 4;

    // staging address pieces: 8 lanes/row, 16B/lane
    const int srow = tid >> 3;            // 0..31 (row within 32-row pass)
    const int scol = (tid & 7) * 8;       // short offset within 64-col slice

    floatx4 acc[4][4];
    #pragma unroll
    for (int i = 0; i < 4; ++i)
        #pragma unroll
        for (int j = 0; j < 4; ++j)
            acc[i][j] = (floatx4){0.f, 0.f, 0.f, 0.f};

    for (int k0 = 0; k0 < 256; k0 += 64) {
        #pragma unroll
        for (int p = 0; p < 4; ++p) {
            int arow = m0 + p * 32 + srow;
            if (arow > NN - 1) arow = NN - 1;             // clamp, masked later
            gload_lds16(Xb + (size_t)arow * 256 + k0 + scol,
                        (char*)sA + p * 4096 + wave * 1024);
            gload_lds16(W + (size_t)(p * 32 + srow) * 256 + k0 + scol,
                        (char*)sB + p * 4096 + wave * 1024);
        }
        __syncthreads();

        #pragma unroll
        for (int ks = 0; ks < 2; ++ks) {
            bf16x8 af[4], bfr[4];
            #pragma unroll
            for (int i = 0; i < 4; ++i)
                af[i] = *(const bf16x8*)&sA[(wm + i * 16 + lr) * 64 + ks * 32 + lq * 8];
            #pragma unroll
            for (int j = 0; j < 4; ++j)
                bfr[j] = *(const bf16x8*)&sB[(wn + j * 16 + lr) * 64 + ks * 32 + lq * 8];
            #pragma unroll
            for (int i = 0; i < 4; ++i)
                #pragma unroll
                for (int j = 0; j < 4; ++j)
                    acc[i][j] = __builtin_amdgcn_mfma_f32_16x16x32_bf16(
                        af[i], bfr[j], acc[i][j], 0, 0, 0);
        }
        __syncthreads();
    }

    if (mat < 3) {
        unsigned short* __restrict__ Cb = (mat == 0) ? qb : (mat == 1) ? kb : vb;
        unsigned short* sOut = (unsigned short*)smem;   // [32][136]
        for (int ch = 0; ch < 4; ++ch) {
            __syncthreads();
            if ((ch >> 1) == (wave & 1)) {
                int ibase = (ch & 1) * 2;
                #pragma unroll
                for (int ii = 0; ii < 2; ++ii) {
                    int i = ibase + ii;
                    #pragma unroll
                    for (int j = 0; j < 4; ++j) {
                        int col = wn + j * 16 + lr;
                        float bb = bias[colbase + col];
                        #pragma unroll
                        for (int r = 0; r < 4; ++r) {
                            int rowc = ii * 16 + lq * 4 + r;
                            sOut[rowc * 136 + col] = f2bf(acc[i][j][r] + bb);
                        }
                    }
                }
            }
            __syncthreads();
            #pragma unroll
            for (int p = 0; p < 2; ++p) {
                int rowc = p * 16 + (tid >> 4);
                int off  = (tid & 15) * 8;
                int grow = m0 + ch * 32 + rowc;
                if (grow < NN) {
                    uint4 u = *(const uint4*)&sOut[rowc * 136 + off];
                    *(uint4*)&Cb[(size_t)grow * 256 + colbase + off] = u;
                }
            }
        }
    } else {
        float* sOutF = (float*)smem;    // [16][132]
        for (int ch = 0; ch < 8; ++ch) {
            __syncthreads();
            if ((ch >> 2) == (wave & 1)) {
                int i = ch & 3;
                #pragma unroll
                for (int j = 0; j < 4; ++j) {
                    int col = wn + j * 16 + lr;
                    float bb = bias[colbase + col];
                    #pragma unroll
                    for (int r = 0; r < 4; ++r) {
                        int rowc = lq * 4 + r;
                        sOutF[rowc * 132 + col] = acc[i][j][r] + bb;
                    }
                }
            }
            __syncthreads();
            #pragma unroll
            for (int p = 0; p < 2; ++p) {
                int rowc = p * 8 + (tid >> 5);
                int off  = (tid & 31) * 4;
                int grow = m0 + ch * 16 + rowc;
                if (grow < NN) {
                    float4 f = *(const float4*)&sOutF[rowc * 132 + off];
                    *(float4*)&outS[(size_t)grow * 256 + colbase + off] = f;
                }
            }
        }
    }
}

// ---------------------------------------------------------------------------
// Edge projection GEMM. A-tile sources:
//   k0=0   : bf16(cos(tv*w_time + b_time)) built in regs, linear ds_write
//            (VALU-only, L2-hot scalars -> short chain, proven clean writes)
//   k0=64+ : efb bf16 [E,128] via global_load_lds (async, proven-fast path;
//            the fp32 load->pack->ds_write chain inside the GEMM was the
//            r6/r7 regression: 2 TB/s at ~2 blocks/CU residency)
// B = Web via global_load_lds. Values bit-identical to rounds 1-5.
// ---------------------------------------------------------------------------
__global__ __launch_bounds__(256)
void edge_gemm_kernel(const float* __restrict__ tvals,
                      const float* __restrict__ w_time,
                      const float* __restrict__ b_time,
                      const unsigned short* __restrict__ efb,
                      const unsigned short* __restrict__ Web,
                      unsigned short* __restrict__ epb)
{
    const int m0 = blockIdx.x * 128;
    const int n0 = blockIdx.y * 128;

    __shared__ __align__(16) unsigned char smem[32768];
    short* sA = (short*)smem;             // [128][64] linear
    short* sB = (short*)(smem + 16384);   // [128][64] linear

    const int tid  = threadIdx.x;
    const int lane = tid & 63;
    const int wave = tid >> 6;
    const int wm   = (wave & 1) * 64;
    const int wn   = (wave >> 1) * 64;
    const int lr   = lane & 15;
    const int lq   = lane >> 4;

    const int srow = tid >> 3;           // 0..31 (row within 32-row pass)
    const int scol = (tid & 7) * 8;      // short offset within 64-col slice

    floatx4 acc[4][4];
    #pragma unroll
    for (int i = 0; i < 4; ++i)
        #pragma unroll
        for (int j = 0; j < 4; ++j)
            acc[i][j] = (floatx4){0.f, 0.f, 0.f, 0.f};

    for (int k0 = 0; k0 < 192; k0 += 64) {
        // ---- B tile: Web rows n0..n0+127, cols k0..k0+63 (async to LDS) ----
        #pragma unroll
        for (int p = 0; p < 4; ++p)
            gload_lds16(Web + (size_t)(n0 + p * 32 + srow) * 192 + k0 + scol,
                        (char*)sB + p * 4096 + wave * 1024);

        if (k0 == 0) {
            // ---- time-encoder slice: cols scol..scol+7 of cos(tv*w+b) ----
            float w8[8], b8[8];
            #pragma unroll
            for (int j = 0; j < 8; ++j) {
                w8[j] = w_time[scol + j];
                b8[j] = b_time[scol + j];
            }
            #pragma unroll
            for (int p = 0; p < 4; ++p) {
                float tvv = tvals[m0 + p * 32 + srow];
                unsigned pk[4];
                #pragma unroll
                for (int j = 0; j < 4; ++j) {
                    float a = cosf(fmaf(tvv, w8[2 * j],     b8[2 * j]));
                    float b = cosf(fmaf(tvv, w8[2 * j + 1], b8[2 * j + 1]));
                    pk[j] = pack2bf(a, b);
                }
                *(uint4*)&sA[p * 2048 + tid * 8] = make_uint4(pk[0], pk[1], pk[2], pk[3]);
            }
        } else {
            // ---- edge-feat slice: bf16 efb via async global_load_lds ----
            #pragma unroll
            for (int p = 0; p < 4; ++p)
                gload_lds16(efb + (size_t)(m0 + p * 32 + srow) * 128 + (k0 - 64) + scol,
                            (char*)sA + p * 4096 + wave * 1024);
        }
        __syncthreads();

        #pragma unroll
        for (int ks = 0; ks < 2; ++ks) {
            bf16x8 af[4], bfr[4];
            #pragma unroll
            for (int i = 0; i < 4; ++i)
                af[i] = *(const bf16x8*)&sA[(wm + i * 16 + lr) * 64 + ks * 32 + lq * 8];
            #pragma unroll
            for (int j = 0; j < 4; ++j)
                bfr[j] = *(const bf16x8*)&sB[(wn + j * 16 + lr) * 64 + ks * 32 + lq * 8];
            #pragma unroll
            for (int i = 0; i < 4; ++i)
                #pragma unroll
                for (int j = 0; j < 4; ++j)
                    acc[i][j] = __builtin_amdgcn_mfma_f32_16x16x32_bf16(
                        af[i], bfr[j], acc[i][j], 0, 0, 0);
        }
        __syncthreads();
    }

    unsigned short* sOut = (unsigned short*)smem;   // [32][136]
    for (int ch = 0; ch < 4; ++ch) {
        __syncthreads();
        if ((ch >> 1) == (wave & 1)) {
            int ibase = (ch & 1) * 2;
            #pragma unroll
            for (int ii = 0; ii < 2; ++ii) {
                int i = ibase + ii;
                #pragma unroll
                for (int j = 0; j < 4; ++j) {
                    int col = wn + j * 16 + lr;
                    #pragma unroll
                    for (int r = 0; r < 4; ++r) {
                        int rowc = ii * 16 + lq * 4 + r;
                        sOut[rowc * 136 + col] = f2bf(acc[i][j][r]);
                    }
                }
            }
        }
        __syncthreads();
        #pragma unroll
        for (int p = 0; p < 2; ++p) {
            int rowc = p * 16 + (tid >> 4);
            int off  = (tid & 15) * 8;
            int grow = m0 + ch * 32 + rowc;
            uint4 u = *(const uint4*)&sOut[rowc * 136 + off];
            *(uint4*)&epb[(size_t)grow * 256 + n0 + off] = u;
        }
    }
}

// ---------------------------------------------------------------------------
// CSR build: histogram, 3-phase parallel scan, scatter (packs (e,src) int2).
// ---------------------------------------------------------------------------
__global__ __launch_bounds__(256)
void deg_kernel(const int* __restrict__ et, int* __restrict__ deg)
{
    int e = blockIdx.x * 256 + threadIdx.x;
    if (e < NE) atomicAdd(&deg[et[NE + e]], 1);
}

// Phase A: per-block (256-node chunk) sums -> bsum[SCAN_NBLK]
__global__ __launch_bounds__(256)
void blocksum_kernel(const int* __restrict__ deg, int* __restrict__ bsum)
{
    int idx = blockIdx.x * 256 + threadIdx.x;
    int v = (idx < NN) ? deg[idx] : 0;
    #pragma unroll
    for (int off = 1; off < 64; off <<= 1) v += __shfl_xor(v, off);
    __shared__ int s[4];
    if ((threadIdx.x & 63) == 0) s[threadIdx.x >> 6] = v;
    __syncthreads();
    if (threadIdx.x == 0) bsum[blockIdx.x] = s[0] + s[1] + s[2] + s[3];
}

// Phase B: single small block exclusive-scans bsum in place; writes total.
__global__ __launch_bounds__(256)
void bscan_kernel(int* __restrict__ bsum, int* __restrict__ rowstart)
{
    __shared__ int s[256];
    int t = threadIdx.x;
    int v = (t < SCAN_NBLK) ? bsum[t] : 0;
    s[t] = v;
    __syncthreads();
    #pragma unroll
    for (int off = 1; off < 256; off <<= 1) {
        int u = (t >= off) ? s[t - off] : 0;
        __syncthreads();
        s[t] += u;
        __syncthreads();
    }
    if (t < SCAN_NBLK) bsum[t] = (t == 0) ? 0 : s[t - 1];   // exclusive
    if (t == 0) rowstart[NN] = s[SCAN_NBLK - 1];            // total = NE
}

// Phase C: per-chunk exclusive scan + block offset -> rowstart, cursor.
__global__ __launch_bounds__(256)
void chunkscan_kernel(const int* __restrict__ deg, const int* __restrict__ bsum,
                      int* __restrict__ rowstart, int* __restrict__ cursor)
{
    __shared__ int s[256];
    int t = threadIdx.x;
    int idx = blockIdx.x * 256 + t;
    int v = (idx < NN) ? deg[idx] : 0;
    s[t] = v;
    __syncthreads();
    #pragma unroll
    for (int off = 1; off < 256; off <<= 1) {
        int u = (t >= off) ? s[t - off] : 0;
        __syncthreads();
        s[t] += u;
        __syncthreads();
    }
    if (idx < NN) {
        int ex = bsum[blockIdx.x] + s[t] - v;   // exclusive within-chunk + offset
        rowstart[idx] = ex;
        cursor[idx]   = ex;
    }
}

__global__ __launch_bounds__(256)
void scatter_kernel(const int* __restrict__ et,
                    int* __restrict__ cursor,
                    int2* __restrict__ eslist)
{
    int e = blockIdx.x * 256 + threadIdx.x;
    if (e < NE) {
        int d   = et[NE + e];
        int pos = atomicAdd(&cursor[d], 1);
        eslist[pos] = make_int2(e, et[e]);   // (edge id, src node)
    }
}

// ---------------------------------------------------------------------------
// Fused attention + aggregation + skip.
// One wave per dst node; lane-half h handles edge i+h (same row -> no trip
// divergence); each lane covers 8 channels (16B uint4 gathers); x2 pair
// unroll = 4 edges in flight. Head = 4 lanes (32 ch): 2-shfl reduce.
// Cross-half combine via shfl_xor(32) once per node.
// ---------------------------------------------------------------------------
static __device__ __forceinline__ void edge_proc(
    uint4 ku, uint4 vu, uintx4 eu, const float* q, float mask,
    float* a, float& accd)
{
    float pe0 = bflo(eu[0]), pe1 = bfhi(eu[0]);
    float pe2 = bflo(eu[1]), pe3 = bfhi(eu[1]);
    float pe4 = bflo(eu[2]), pe5 = bfhi(eu[2]);
    float pe6 = bflo(eu[3]), pe7 = bfhi(eu[3]);

    float part;
    part = q[0] * (bflo(ku.x) + pe0);
    part = fmaf(q[1], bfhi(ku.x) + pe1, part);
    part = fmaf(q[2], bflo(ku.y) + pe2, part);
    part = fmaf(q[3], bfhi(ku.y) + pe3, part);
    part = fmaf(q[4], bflo(ku.z) + pe4, part);
    part = fmaf(q[5], bfhi(ku.z) + pe5, part);
    part = fmaf(q[6], bflo(ku.w) + pe6, part);
    part = fmaf(q[7], bfhi(ku.w) + pe7, part);
    part += __shfl_xor(part, 1);
    part += __shfl_xor(part, 2);

    float ea = __expf(part * 0.17677669529663687f) * mask;  // 1/sqrt(32)

    a[0] = fmaf(ea, bflo(vu.x) + pe0, a[0]);
    a[1] = fmaf(ea, bfhi(vu.x) + pe1, a[1]);
    a[2] = fmaf(ea, bflo(vu.y) + pe2, a[2]);
    a[3] = fmaf(ea, bfhi(vu.y) + pe3, a[3]);
    a[4] = fmaf(ea, bflo(vu.z) + pe4, a[4]);
    a[5] = fmaf(ea, bfhi(vu.z) + pe5, a[5]);
    a[6] = fmaf(ea, bflo(vu.w) + pe6, a[6]);
    a[7] = fmaf(ea, bfhi(vu.w) + pe7, a[7]);
    accd += ea;
}

__global__ __launch_bounds__(256)
void fused_agg_kernel(const int2* __restrict__ eslist,
                      const int* __restrict__ rowstart,
                      const unsigned short* __restrict__ qb,
                      const unsigned short* __restrict__ kb,
                      const unsigned short* __restrict__ vb,
                      const unsigned short* __restrict__ epb,
                      float* __restrict__ out)
{
    const int n = blockIdx.x * 4 + (threadIdx.x >> 6);
    if (n >= NN) return;
    const int lane = threadIdx.x & 63;
    const int half = lane >> 5;         // 0: edge i, 1: edge i+1
    const int co   = (lane & 31) * 8;   // my 8 channels

    uint4 qu = *(const uint4*)(qb + (size_t)n * 256 + co);
    float q[8] = { bflo(qu.x), bfhi(qu.x), bflo(qu.y), bfhi(qu.y),
                   bflo(qu.z), bfhi(qu.z), bflo(qu.w), bfhi(qu.w) };

    float a[8] = {0.f, 0.f, 0.f, 0.f, 0.f, 0.f, 0.f, 0.f};
    float accd = 0.f;

    const int s0 = rowstart[n];
    const int s1 = rowstart[n + 1];

    int i = s0;
    for (; i + 4 <= s1; i += 4) {
        // 4 edges in flight: issue all gathers before any compute
        const int2 pA = eslist[i + half];
        const int2 pB = eslist[i + 2 + half];
        uint4 kA = *(const uint4*)(kb + (size_t)pA.y * 256 + co);
        uint4 vA = *(const uint4*)(vb + (size_t)pA.y * 256 + co);
        uintx4 eA = __builtin_nontemporal_load(
                        (const uintx4*)(epb + (size_t)pA.x * 256 + co));
        uint4 kB = *(const uint4*)(kb + (size_t)pB.y * 256 + co);
        uint4 vB = *(const uint4*)(vb + (size_t)pB.y * 256 + co);
        uintx4 eB = __builtin_nontemporal_load(
                        (const uintx4*)(epb + (size_t)pB.x * 256 + co));

        edge_proc(kA, vA, eA, q, 1.f, a, accd);
        edge_proc(kB, vB, eB, q, 1.f, a, accd);
    }
    for (; i + 2 <= s1; i += 2) {
        const int2 pA = eslist[i + half];
        uint4 kA = *(const uint4*)(kb + (size_t)pA.y * 256 + co);
        uint4 vA = *(const uint4*)(vb + (size_t)pA.y * 256 + co);
        uintx4 eA = __builtin_nontemporal_load(
                        (const uintx4*)(epb + (size_t)pA.x * 256 + co));
        edge_proc(kA, vA, eA, q, 1.f, a, accd);
    }
    if (i < s1) {
        // masked pair: hi half loads the same edge but contributes 0
        int idx = i + half;
        float mask = (idx < s1) ? 1.f : 0.f;
        if (idx >= s1) idx = s1 - 1;
        const int2 pA = eslist[idx];
        uint4 kA = *(const uint4*)(kb + (size_t)pA.y * 256 + co);
        uint4 vA = *(const uint4*)(vb + (size_t)pA.y * 256 + co);
        uintx4 eA = __builtin_nontemporal_load(
                        (const uintx4*)(epb + (size_t)pA.x * 256 + co));
        edge_proc(kA, vA, eA, q, mask, a, accd);
    }

    // combine lane-halves (same channels, same head in both halves)
    #pragma unroll
    for (int j = 0; j < 8; ++j) a[j] += __shfl_xor(a[j], 32);
    accd += __shfl_xor(accd, 32);

    if (half == 0) {
        const float inv = 1.f / (accd + 1e-16f);
        float* po = out + (size_t)n * 256 + co;
        float4 o0 = ((const float4*)po)[0];
        float4 o1 = ((const float4*)po)[1];
        o0.x = fmaf(a[0], inv, o0.x);
        o0.y = fmaf(a[1], inv, o0.y);
        o0.z = fmaf(a[2], inv, o0.z);
        o0.w = fmaf(a[3], inv, o0.w);
        o1.x = fmaf(a[4], inv, o1.x);
        o1.y = fmaf(a[5], inv, o1.y);
        o1.z = fmaf(a[6], inv, o1.z);
        o1.w = fmaf(a[7], inv, o1.w);
        ((float4*)po)[0] = o0;
        ((float4*)po)[1] = o1;
    }
}

// ---------------------------------------------------------------------------
extern "C" void kernel_launch(void* const* d_in, const int* in_sizes, int n_in,
                              void* d_out, int out_size, void* d_ws, size_t ws_size,
                              hipStream_t stream)
{
    const int*   et  = (const int*)  d_in[0];
    const float* ef  = (const float*)d_in[1];
    const float* tv  = (const float*)d_in[2];
    const float* nf  = (const float*)d_in[3];
    const float* w_t = (const float*)d_in[4];
    const float* b_t = (const float*)d_in[5];
    const float* Wq  = (const float*)d_in[6];
    const float* bq  = (const float*)d_in[7];
    const float* Wk  = (const float*)d_in[8];
    const float* bk  = (const float*)d_in[9];
    const float* Wv  = (const float*)d_in[10];
    const float* bv  = (const float*)d_in[11];
    const float* We  = (const float*)d_in[12];
    const float* Ws  = (const float*)d_in[13];
    const float* bs  = (const float*)d_in[14];
    float* out = (float*)d_out;

    // ws layout (bf16 buffers then ints); efb [E,128] replaces old eab
    unsigned short* qb  = (unsigned short*)d_ws;
    unsigned short* kb  = qb  + (size_t)NN * 256;
    unsigned short* vb  = kb  + (size_t)NN * 256;
    unsigned short* epb = vb  + (size_t)NN * 256;
    unsigned short* nfb = epb + (size_t)NE * 256;
    unsigned short* efb = nfb + (size_t)NN * 256;
    unsigned short* Wqb = efb + (size_t)NE * 128;
    unsigned short* Wkb = Wqb + 65536;
    unsigned short* Wvb = Wkb + 65536;
    unsigned short* Wsb = Wvb + 65536;
    unsigned short* Web = Wsb + 65536;
    int* deg      = (int*)(Web + 49152);
    int* rowstart = deg + NN;
    int* cursor   = rowstart + NN + 1;
    int2* eslist  = (int2*)(cursor + NN);
    int* bsum     = (int*)(eslist + NE);
    size_t need   = (size_t)((char*)(bsum + SCAN_NBLK) - (char*)d_ws);
    if (ws_size < need) return;

    (void)hipMemsetAsync(deg, 0, (size_t)NN * sizeof(int), stream);

    // --- prep: bf16 conversions (streaming, full TLP) ----------------------
    cvt_bf16_kernel<<<(NN * 256 / 8 + 255) / 256, 256, 0, stream>>>(nf, nfb, NN * 256 / 8);
    cvt_bf16_kernel<<<(NE * 128 / 8 + 255) / 256, 256, 0, stream>>>(ef, efb, NE * 128 / 8);
    cvt_bf16_kernel<<<32, 256, 0, stream>>>(Wq, Wqb, 8192);
    cvt_bf16_kernel<<<32, 256, 0, stream>>>(Wk, Wkb, 8192);
    cvt_bf16_kernel<<<32, 256, 0, stream>>>(Wv, Wvb, 8192);
    cvt_bf16_kernel<<<32, 256, 0, stream>>>(Ws, Wsb, 8192);
    cvt_bf16_kernel<<<24, 256, 0, stream>>>(We, Web, 6144);

    // --- GEMMs -------------------------------------------------------------
    node_gemm_kernel<<<dim3((NN + 127) / 128, 8), 256, 0, stream>>>(
        nfb, Wqb, Wkb, Wvb, Wsb, bq, bk, bv, bs, qb, kb, vb, out);

    edge_gemm_kernel<<<dim3(NE / 128, 2), 256, 0, stream>>>(
        tv, w_t, b_t, efb, Web, epb);

    // --- CSR + fused attention/aggregation ---------------------------------
    deg_kernel<<<(NE + 255) / 256, 256, 0, stream>>>(et, deg);
    blocksum_kernel<<<SCAN_NBLK, 256, 0, stream>>>(deg, bsum);
    bscan_kernel<<<1, 256, 0, stream>>>(bsum, rowstart);
    chunkscan_kernel<<<SCAN_NBLK, 256, 0, stream>>>(deg, bsum, rowstart, cursor);
    scatter_kernel<<<(NE + 255) / 256, 256, 0, stream>>>(et, cursor, eslist);

    fused_agg_kernel<<<(NN + 3) / 4, 256, 0, stream>>>(
        eslist, rowstart, qb, kb, vb, epb, out);
}

// Round 9
// 579.040 us; speedup vs baseline: 1.0766x; 1.0766x over previous
//
#include <hip/hip_runtime.h>
#include <hip/hip_bf16.h>
#include <math.h>

#define NN 50000
#define NE 320000
#define SCAN_NBLK ((NN + 255) / 256)   // 196

typedef __attribute__((ext_vector_type(8))) short bf16x8;   // 8 bf16 (4 VGPRs)
typedef __attribute__((ext_vector_type(4))) float floatx4;  // MFMA C/D
typedef __attribute__((ext_vector_type(4))) unsigned int uintx4;  // true vector type
                                                                  // (nontemporal builtin needs it)

static __device__ __forceinline__ unsigned pack2bf(float a, float b) {
    __hip_bfloat162 h = __float22bfloat162_rn(make_float2(a, b));
    return *reinterpret_cast<unsigned*>(&h);
}
static __device__ __forceinline__ unsigned short f2bf(float x) {
    __hip_bfloat16 h = __float2bfloat16(x);
    return *reinterpret_cast<unsigned short*>(&h);
}
static __device__ __forceinline__ float bf2f(unsigned short u) {
    return __uint_as_float(((unsigned)u) << 16);
}
// unpack a uint holding two bf16: low short -> float, high short -> float
static __device__ __forceinline__ float bflo(unsigned u) {
    return __uint_as_float(u << 16);
}
static __device__ __forceinline__ float bfhi(unsigned u) {
    return __uint_as_float(u & 0xffff0000u);
}
// async global->LDS, 16B per lane; lds dest = wave-uniform base + lane*16
static __device__ __forceinline__ void gload_lds16(const void* g, void* l) {
    __builtin_amdgcn_global_load_lds(
        (const __attribute__((address_space(1))) void*)g,
        (__attribute__((address_space(3))) void*)l, 16, 0, 0);
}

// ---------------------------------------------------------------------------
// fp32 -> bf16 streaming convert, 8 elems/thread. n8 = n/8.
// ---------------------------------------------------------------------------
__global__ __launch_bounds__(256)
void cvt_bf16_kernel(const float* __restrict__ in,
                     unsigned short* __restrict__ out, int n8)
{
    int t = blockIdx.x * 256 + threadIdx.x;
    if (t >= n8) return;
    const float4* p = (const float4*)in + (size_t)t * 2;
    float4 a = p[0], b = p[1];
    uint4 u;
    u.x = pack2bf(a.x, a.y); u.y = pack2bf(a.z, a.w);
    u.z = pack2bf(b.x, b.y); u.w = pack2bf(b.z, b.w);
    ((uint4*)out)[t] = u;
}

// ---------------------------------------------------------------------------
// Node projections, pure-bf16 MFMA GEMM with global_load_lds staging.
// C = Xb @ Wb^T (+bias). blockIdx.y = ct: mat = ct>>1, half = ct&1.
// 128x128 tile, BK=64, 4 waves 2x2, 4x4 16x16x32 frags, 2 k-steps per stage.
// ---------------------------------------------------------------------------
__global__ __launch_bounds__(256)
void node_gemm_kernel(const unsigned short* __restrict__ Xb,
                      const unsigned short* __restrict__ Wqb,
                      const unsigned short* __restrict__ Wkb,
                      const unsigned short* __restrict__ Wvb,
                      const unsigned short* __restrict__ Wsb,
                      const float* __restrict__ bq, const float* __restrict__ bk,
                      const float* __restrict__ bv, const float* __restrict__ bs,
                      unsigned short* __restrict__ qb,
                      unsigned short* __restrict__ kb,
                      unsigned short* __restrict__ vb,
                      float* __restrict__ outS)
{
    const int m0  = blockIdx.x * 128;
    const int ct  = blockIdx.y;
    const int mat = ct >> 1, half = ct & 1;
    const int colbase = half * 128;

    const unsigned short* __restrict__ W;
    const float* __restrict__ bias;
    switch (mat) {
        case 0:  W = Wqb; bias = bq; break;
        case 1:  W = Wkb; bias = bk; break;
        case 2:  W = Wvb; bias = bv; break;
        default: W = Wsb; bias = bs; break;
    }
    W += (size_t)colbase * 256;

    __shared__ __align__(16) unsigned char smem[32768];
    short* sA = (short*)smem;             // [128][64]
    short* sB = (short*)(smem + 16384);   // [128][64]

    const int tid  = threadIdx.x;
    const int lane = tid & 63;
    const int wave = tid >> 6;
    const int wm   = (wave & 1) * 64;
    const int wn   = (wave >> 1) * 64;
    const int lr   = lane & 15;
    const int lq   = lane >> 4;

    // staging address pieces: 8 lanes/row, 16B/lane
    const int srow = tid >> 3;            // 0..31 (row within 32-row pass)
    const int scol = (tid & 7) * 8;       // short offset within 64-col slice

    floatx4 acc[4][4];
    #pragma unroll
    for (int i = 0; i < 4; ++i)
        #pragma unroll
        for (int j = 0; j < 4; ++j)
            acc[i][j] = (floatx4){0.f, 0.f, 0.f, 0.f};

    for (int k0 = 0; k0 < 256; k0 += 64) {
        #pragma unroll
        for (int p = 0; p < 4; ++p) {
            int arow = m0 + p * 32 + srow;
            if (arow > NN - 1) arow = NN - 1;             // clamp, masked later
            gload_lds16(Xb + (size_t)arow * 256 + k0 + scol,
                        (char*)sA + p * 4096 + wave * 1024);
            gload_lds16(W + (size_t)(p * 32 + srow) * 256 + k0 + scol,
                        (char*)sB + p * 4096 + wave * 1024);
        }
        __syncthreads();

        #pragma unroll
        for (int ks = 0; ks < 2; ++ks) {
            bf16x8 af[4], bfr[4];
            #pragma unroll
            for (int i = 0; i < 4; ++i)
                af[i] = *(const bf16x8*)&sA[(wm + i * 16 + lr) * 64 + ks * 32 + lq * 8];
            #pragma unroll
            for (int j = 0; j < 4; ++j)
                bfr[j] = *(const bf16x8*)&sB[(wn + j * 16 + lr) * 64 + ks * 32 + lq * 8];
            #pragma unroll
            for (int i = 0; i < 4; ++i)
                #pragma unroll
                for (int j = 0; j < 4; ++j)
                    acc[i][j] = __builtin_amdgcn_mfma_f32_16x16x32_bf16(
                        af[i], bfr[j], acc[i][j], 0, 0, 0);
        }
        __syncthreads();
    }

    if (mat < 3) {
        unsigned short* __restrict__ Cb = (mat == 0) ? qb : (mat == 1) ? kb : vb;
        unsigned short* sOut = (unsigned short*)smem;   // [32][136]
        for (int ch = 0; ch < 4; ++ch) {
            __syncthreads();
            if ((ch >> 1) == (wave & 1)) {
                int ibase = (ch & 1) * 2;
                #pragma unroll
                for (int ii = 0; ii < 2; ++ii) {
                    int i = ibase + ii;
                    #pragma unroll
                    for (int j = 0; j < 4; ++j) {
                        int col = wn + j * 16 + lr;
                        float bb = bias[colbase + col];
                        #pragma unroll
                        for (int r = 0; r < 4; ++r) {
                            int rowc = ii * 16 + lq * 4 + r;
                            sOut[rowc * 136 + col] = f2bf(acc[i][j][r] + bb);
                        }
                    }
                }
            }
            __syncthreads();
            #pragma unroll
            for (int p = 0; p < 2; ++p) {
                int rowc = p * 16 + (tid >> 4);
                int off  = (tid & 15) * 8;
                int grow = m0 + ch * 32 + rowc;
                if (grow < NN) {
                    uint4 u = *(const uint4*)&sOut[rowc * 136 + off];
                    *(uint4*)&Cb[(size_t)grow * 256 + colbase + off] = u;
                }
            }
        }
    } else {
        float* sOutF = (float*)smem;    // [16][132]
        for (int ch = 0; ch < 8; ++ch) {
            __syncthreads();
            if ((ch >> 2) == (wave & 1)) {
                int i = ch & 3;
                #pragma unroll
                for (int j = 0; j < 4; ++j) {
                    int col = wn + j * 16 + lr;
                    float bb = bias[colbase + col];
                    #pragma unroll
                    for (int r = 0; r < 4; ++r) {
                        int rowc = lq * 4 + r;
                        sOutF[rowc * 132 + col] = acc[i][j][r] + bb;
                    }
                }
            }
            __syncthreads();
            #pragma unroll
            for (int p = 0; p < 2; ++p) {
                int rowc = p * 8 + (tid >> 5);
                int off  = (tid & 31) * 4;
                int grow = m0 + ch * 16 + rowc;
                if (grow < NN) {
                    float4 f = *(const float4*)&sOutF[rowc * 132 + off];
                    *(float4*)&outS[(size_t)grow * 256 + colbase + off] = f;
                }
            }
        }
    }
}

// ---------------------------------------------------------------------------
// Edge projection GEMM, full 128x256 output per block (8 waves, 512 thr).
// A (128xK) staged ONCE per block: k0=0 slice = cos time-encoder built in
// regs; k0=64/128 = ef fp32 read + pack (r7 dataflow, but A-traffic halved
// vs y-grid=2 split). All LDS writes follow the linear base+tid*16 pattern
// (bank-sequential; r6's strided ds_write conflict avoided).
// B = Web [256][192] via global_load_lds (L2-resident, ~96KB).
// LDS: sA 16KB + sB 32KB = 48KB -> 3 blocks/CU ceiling.
// ---------------------------------------------------------------------------
__global__ __launch_bounds__(512)
void edge_gemm_kernel(const float* __restrict__ tvals,
                      const float* __restrict__ w_time,
                      const float* __restrict__ b_time,
                      const float* __restrict__ ef,
                      const unsigned short* __restrict__ Web,
                      unsigned short* __restrict__ epb)
{
    const int m0 = blockIdx.x * 128;

    __shared__ __align__(16) unsigned char smem[49152];
    short* sA = (short*)smem;             // [128][64] linear
    short* sB = (short*)(smem + 16384);   // [256][64] linear

    const int tid  = threadIdx.x;         // 0..511
    const int lane = tid & 63;
    const int wave = tid >> 6;            // 0..7
    const int wm   = (wave & 1) * 64;     // 2 m-positions
    const int wn   = (wave >> 1) * 64;    // 4 n-positions (0..192)
    const int lr   = lane & 15;
    const int lq   = lane >> 4;

    floatx4 acc[4][4];
    #pragma unroll
    for (int i = 0; i < 4; ++i)
        #pragma unroll
        for (int j = 0; j < 4; ++j)
            acc[i][j] = (floatx4){0.f, 0.f, 0.f, 0.f};

    for (int k0 = 0; k0 < 192; k0 += 64) {
        // ---- B tile: Web rows 0..255, cols k0..k0+63, 4 async passes ----
        #pragma unroll
        for (int p = 0; p < 4; ++p)
            gload_lds16(Web + (size_t)(p * 64 + (tid >> 3)) * 192 + k0 + (tid & 7) * 8,
                        (char*)sB + p * 8192 + wave * 1024);

        // ---- A tile: 2 passes, row = p*64 + (tid>>3), cols (tid&7)*8 ----
        if (k0 == 0) {
            #pragma unroll
            for (int p = 0; p < 2; ++p) {
                int   row = p * 64 + (tid >> 3);
                float tvv = tvals[m0 + row];
                int   c0  = (tid & 7) * 8;
                float4 w0 = *(const float4*)(w_time + c0);
                float4 w1 = *(const float4*)(w_time + c0 + 4);
                float4 b0 = *(const float4*)(b_time + c0);
                float4 b1 = *(const float4*)(b_time + c0 + 4);
                uint4 u;
                u.x = pack2bf(cosf(fmaf(tvv, w0.x, b0.x)), cosf(fmaf(tvv, w0.y, b0.y)));
                u.y = pack2bf(cosf(fmaf(tvv, w0.z, b0.z)), cosf(fmaf(tvv, w0.w, b0.w)));
                u.z = pack2bf(cosf(fmaf(tvv, w1.x, b1.x)), cosf(fmaf(tvv, w1.y, b1.y)));
                u.w = pack2bf(cosf(fmaf(tvv, w1.z, b1.z)), cosf(fmaf(tvv, w1.w, b1.w)));
                *(uint4*)&sA[p * 4096 + tid * 8] = u;
            }
        } else {
            // issue all 4 float4 loads first (MLP), then pack + linear write
            float4 f[4];
            #pragma unroll
            for (int p = 0; p < 2; ++p) {
                const float4* src = (const float4*)(ef
                    + (size_t)(m0 + p * 64 + (tid >> 3)) * 128 + (k0 - 64) + (tid & 7) * 8);
                f[2 * p]     = src[0];
                f[2 * p + 1] = src[1];
            }
            #pragma unroll
            for (int p = 0; p < 2; ++p) {
                uint4 u;
                u.x = pack2bf(f[2 * p].x,     f[2 * p].y);
                u.y = pack2bf(f[2 * p].z,     f[2 * p].w);
                u.z = pack2bf(f[2 * p + 1].x, f[2 * p + 1].y);
                u.w = pack2bf(f[2 * p + 1].z, f[2 * p + 1].w);
                *(uint4*)&sA[p * 4096 + tid * 8] = u;
            }
        }
        __syncthreads();

        #pragma unroll
        for (int ks = 0; ks < 2; ++ks) {
            bf16x8 af[4], bfr[4];
            #pragma unroll
            for (int i = 0; i < 4; ++i)
                af[i] = *(const bf16x8*)&sA[(wm + i * 16 + lr) * 64 + ks * 32 + lq * 8];
            #pragma unroll
            for (int j = 0; j < 4; ++j)
                bfr[j] = *(const bf16x8*)&sB[(wn + j * 16 + lr) * 64 + ks * 32 + lq * 8];
            #pragma unroll
            for (int i = 0; i < 4; ++i)
                #pragma unroll
                for (int j = 0; j < 4; ++j)
                    acc[i][j] = __builtin_amdgcn_mfma_f32_16x16x32_bf16(
                        af[i], bfr[j], acc[i][j], 0, 0, 0);
        }
        __syncthreads();
    }

    // epilogue: 4 chunks of 32 rows x 256 cols via LDS bounce [32][264]
    unsigned short* sOut = (unsigned short*)smem;
    for (int ch = 0; ch < 4; ++ch) {
        __syncthreads();
        if ((wave & 1) == (ch >> 1)) {
            int ibase = (ch & 1) * 2;
            #pragma unroll
            for (int ii = 0; ii < 2; ++ii) {
                int i = ibase + ii;
                #pragma unroll
                for (int j = 0; j < 4; ++j) {
                    int col = wn + j * 16 + lr;
                    #pragma unroll
                    for (int r = 0; r < 4; ++r) {
                        int rowc = ii * 16 + lq * 4 + r;
                        sOut[rowc * 264 + col] = f2bf(acc[i][j][r]);
                    }
                }
            }
        }
        __syncthreads();
        #pragma unroll
        for (int p = 0; p < 2; ++p) {
            int rl   = p * 16 + (tid >> 5);
            int off  = (tid & 31) * 8;
            int grow = m0 + ch * 32 + rl;
            uint4 u = *(const uint4*)&sOut[rl * 264 + off];
            *(uint4*)&epb[(size_t)grow * 256 + off] = u;
        }
    }
}

// ---------------------------------------------------------------------------
// CSR build: histogram, 3-phase parallel scan, scatter (packs (e,src) int2).
// ---------------------------------------------------------------------------
__global__ __launch_bounds__(256)
void deg_kernel(const int* __restrict__ et, int* __restrict__ deg)
{
    int e = blockIdx.x * 256 + threadIdx.x;
    if (e < NE) atomicAdd(&deg[et[NE + e]], 1);
}

// Phase A: per-block (256-node chunk) sums -> bsum[SCAN_NBLK]
__global__ __launch_bounds__(256)
void blocksum_kernel(const int* __restrict__ deg, int* __restrict__ bsum)
{
    int idx = blockIdx.x * 256 + threadIdx.x;
    int v = (idx < NN) ? deg[idx] : 0;
    #pragma unroll
    for (int off = 1; off < 64; off <<= 1) v += __shfl_xor(v, off);
    __shared__ int s[4];
    if ((threadIdx.x & 63) == 0) s[threadIdx.x >> 6] = v;
    __syncthreads();
    if (threadIdx.x == 0) bsum[blockIdx.x] = s[0] + s[1] + s[2] + s[3];
}

// Phase B: single small block exclusive-scans bsum in place; writes total.
__global__ __launch_bounds__(256)
void bscan_kernel(int* __restrict__ bsum, int* __restrict__ rowstart)
{
    __shared__ int s[256];
    int t = threadIdx.x;
    int v = (t < SCAN_NBLK) ? bsum[t] : 0;
    s[t] = v;
    __syncthreads();
    #pragma unroll
    for (int off = 1; off < 256; off <<= 1) {
        int u = (t >= off) ? s[t - off] : 0;
        __syncthreads();
        s[t] += u;
        __syncthreads();
    }
    if (t < SCAN_NBLK) bsum[t] = (t == 0) ? 0 : s[t - 1];   // exclusive
    if (t == 0) rowstart[NN] = s[SCAN_NBLK - 1];            // total = NE
}

// Phase C: per-chunk exclusive scan + block offset -> rowstart, cursor.
__global__ __launch_bounds__(256)
void chunkscan_kernel(const int* __restrict__ deg, const int* __restrict__ bsum,
                      int* __restrict__ rowstart, int* __restrict__ cursor)
{
    __shared__ int s[256];
    int t = threadIdx.x;
    int idx = blockIdx.x * 256 + t;
    int v = (idx < NN) ? deg[idx] : 0;
    s[t] = v;
    __syncthreads();
    #pragma unroll
    for (int off = 1; off < 256; off <<= 1) {
        int u = (t >= off) ? s[t - off] : 0;
        __syncthreads();
        s[t] += u;
        __syncthreads();
    }
    if (idx < NN) {
        int ex = bsum[blockIdx.x] + s[t] - v;   // exclusive within-chunk + offset
        rowstart[idx] = ex;
        cursor[idx]   = ex;
    }
}

__global__ __launch_bounds__(256)
void scatter_kernel(const int* __restrict__ et,
                    int* __restrict__ cursor,
                    int2* __restrict__ eslist)
{
    int e = blockIdx.x * 256 + threadIdx.x;
    if (e < NE) {
        int d   = et[NE + e];
        int pos = atomicAdd(&cursor[d], 1);
        eslist[pos] = make_int2(e, et[e]);   // (edge id, src node)
    }
}

// ---------------------------------------------------------------------------
// Fused attention + aggregation + skip.
// One wave per dst node; lane-half h handles edge i+h (same row -> no trip
// divergence); each lane covers 8 channels (16B uint4 gathers); x2 pair
// unroll = 4 edges in flight. Head = 4 lanes (32 ch): 2-shfl reduce.
// Cross-half combine via shfl_xor(32) once per node.
// ---------------------------------------------------------------------------
static __device__ __forceinline__ void edge_proc(
    uint4 ku, uint4 vu, uintx4 eu, const float* q, float mask,
    float* a, float& accd)
{
    float pe0 = bflo(eu[0]), pe1 = bfhi(eu[0]);
    float pe2 = bflo(eu[1]), pe3 = bfhi(eu[1]);
    float pe4 = bflo(eu[2]), pe5 = bfhi(eu[2]);
    float pe6 = bflo(eu[3]), pe7 = bfhi(eu[3]);

    float part;
    part = q[0] * (bflo(ku.x) + pe0);
    part = fmaf(q[1], bfhi(ku.x) + pe1, part);
    part = fmaf(q[2], bflo(ku.y) + pe2, part);
    part = fmaf(q[3], bfhi(ku.y) + pe3, part);
    part = fmaf(q[4], bflo(ku.z) + pe4, part);
    part = fmaf(q[5], bfhi(ku.z) + pe5, part);
    part = fmaf(q[6], bflo(ku.w) + pe6, part);
    part = fmaf(q[7], bfhi(ku.w) + pe7, part);
    part += __shfl_xor(part, 1);
    part += __shfl_xor(part, 2);

    float ea = __expf(part * 0.17677669529663687f) * mask;  // 1/sqrt(32)

    a[0] = fmaf(ea, bflo(vu.x) + pe0, a[0]);
    a[1] = fmaf(ea, bfhi(vu.x) + pe1, a[1]);
    a[2] = fmaf(ea, bflo(vu.y) + pe2, a[2]);
    a[3] = fmaf(ea, bfhi(vu.y) + pe3, a[3]);
    a[4] = fmaf(ea, bflo(vu.z) + pe4, a[4]);
    a[5] = fmaf(ea, bfhi(vu.z) + pe5, a[5]);
    a[6] = fmaf(ea, bflo(vu.w) + pe6, a[6]);
    a[7] = fmaf(ea, bfhi(vu.w) + pe7, a[7]);
    accd += ea;
}

__global__ __launch_bounds__(256)
void fused_agg_kernel(const int2* __restrict__ eslist,
                      const int* __restrict__ rowstart,
                      const unsigned short* __restrict__ qb,
                      const unsigned short* __restrict__ kb,
                      const unsigned short* __restrict__ vb,
                      const unsigned short* __restrict__ epb,
                      float* __restrict__ out)
{
    const int n = blockIdx.x * 4 + (threadIdx.x >> 6);
    if (n >= NN) return;
    const int lane = threadIdx.x & 63;
    const int half = lane >> 5;         // 0: edge i, 1: edge i+1
    const int co   = (lane & 31) * 8;   // my 8 channels

    uint4 qu = *(const uint4*)(qb + (size_t)n * 256 + co);
    float q[8] = { bflo(qu.x), bfhi(qu.x), bflo(qu.y), bfhi(qu.y),
                   bflo(qu.z), bfhi(qu.z), bflo(qu.w), bfhi(qu.w) };

    float a[8] = {0.f, 0.f, 0.f, 0.f, 0.f, 0.f, 0.f, 0.f};
    float accd = 0.f;

    const int s0 = rowstart[n];
    const int s1 = rowstart[n + 1];

    int i = s0;
    for (; i + 4 <= s1; i += 4) {
        // 4 edges in flight: issue all gathers before any compute
        const int2 pA = eslist[i + half];
        const int2 pB = eslist[i + 2 + half];
        uint4 kA = *(const uint4*)(kb + (size_t)pA.y * 256 + co);
        uint4 vA = *(const uint4*)(vb + (size_t)pA.y * 256 + co);
        uintx4 eA = __builtin_nontemporal_load(
                        (const uintx4*)(epb + (size_t)pA.x * 256 + co));
        uint4 kB = *(const uint4*)(kb + (size_t)pB.y * 256 + co);
        uint4 vB = *(const uint4*)(vb + (size_t)pB.y * 256 + co);
        uintx4 eB = __builtin_nontemporal_load(
                        (const uintx4*)(epb + (size_t)pB.x * 256 + co));

        edge_proc(kA, vA, eA, q, 1.f, a, accd);
        edge_proc(kB, vB, eB, q, 1.f, a, accd);
    }
    for (; i + 2 <= s1; i += 2) {
        const int2 pA = eslist[i + half];
        uint4 kA = *(const uint4*)(kb + (size_t)pA.y * 256 + co);
        uint4 vA = *(const uint4*)(vb + (size_t)pA.y * 256 + co);
        uintx4 eA = __builtin_nontemporal_load(
                        (const uintx4*)(epb + (size_t)pA.x * 256 + co));
        edge_proc(kA, vA, eA, q, 1.f, a, accd);
    }
    if (i < s1) {
        // masked pair: hi half loads the same edge but contributes 0
        int idx = i + half;
        float mask = (idx < s1) ? 1.f : 0.f;
        if (idx >= s1) idx = s1 - 1;
        const int2 pA = eslist[idx];
        uint4 kA = *(const uint4*)(kb + (size_t)pA.y * 256 + co);
        uint4 vA = *(const uint4*)(vb + (size_t)pA.y * 256 + co);
        uintx4 eA = __builtin_nontemporal_load(
                        (const uintx4*)(epb + (size_t)pA.x * 256 + co));
        edge_proc(kA, vA, eA, q, mask, a, accd);
    }

    // combine lane-halves (same channels, same head in both halves)
    #pragma unroll
    for (int j = 0; j < 8; ++j) a[j] += __shfl_xor(a[j], 32);
    accd += __shfl_xor(accd, 32);

    if (half == 0) {
        const float inv = 1.f / (accd + 1e-16f);
        float* po = out + (size_t)n * 256 + co;
        float4 o0 = ((const float4*)po)[0];
        float4 o1 = ((const float4*)po)[1];
        o0.x = fmaf(a[0], inv, o0.x);
        o0.y = fmaf(a[1], inv, o0.y);
        o0.z = fmaf(a[2], inv, o0.z);
        o0.w = fmaf(a[3], inv, o0.w);
        o1.x = fmaf(a[4], inv, o1.x);
        o1.y = fmaf(a[5], inv, o1.y);
        o1.z = fmaf(a[6], inv, o1.z);
        o1.w = fmaf(a[7], inv, o1.w);
        ((float4*)po)[0] = o0;
        ((float4*)po)[1] = o1;
    }
}

// ---------------------------------------------------------------------------
extern "C" void kernel_launch(void* const* d_in, const int* in_sizes, int n_in,
                              void* d_out, int out_size, void* d_ws, size_t ws_size,
                              hipStream_t stream)
{
    const int*   et  = (const int*)  d_in[0];
    const float* ef  = (const float*)d_in[1];
    const float* tv  = (const float*)d_in[2];
    const float* nf  = (const float*)d_in[3];
    const float* w_t = (const float*)d_in[4];
    const float* b_t = (const float*)d_in[5];
    const float* Wq  = (const float*)d_in[6];
    const float* bq  = (const float*)d_in[7];
    const float* Wk  = (const float*)d_in[8];
    const float* bk  = (const float*)d_in[9];
    const float* Wv  = (const float*)d_in[10];
    const float* bv  = (const float*)d_in[11];
    const float* We  = (const float*)d_in[12];
    const float* Ws  = (const float*)d_in[13];
    const float* bs  = (const float*)d_in[14];
    float* out = (float*)d_out;

    // ws layout (bf16 buffers then ints)
    unsigned short* qb  = (unsigned short*)d_ws;
    unsigned short* kb  = qb  + (size_t)NN * 256;
    unsigned short* vb  = kb  + (size_t)NN * 256;
    unsigned short* epb = vb  + (size_t)NN * 256;
    unsigned short* nfb = epb + (size_t)NE * 256;
    unsigned short* Wqb = nfb + (size_t)NN * 256;
    unsigned short* Wkb = Wqb + 65536;
    unsigned short* Wvb = Wkb + 65536;
    unsigned short* Wsb = Wvb + 65536;
    unsigned short* Web = Wsb + 65536;
    int* deg      = (int*)(Web + 49152);
    int* rowstart = deg + NN;
    int* cursor   = rowstart + NN + 1;
    int2* eslist  = (int2*)(cursor + NN);
    int* bsum     = (int*)(eslist + NE);
    size_t need   = (size_t)((char*)(bsum + SCAN_NBLK) - (char*)d_ws);
    if (ws_size < need) return;

    (void)hipMemsetAsync(deg, 0, (size_t)NN * sizeof(int), stream);

    // --- prep: bf16 conversions -------------------------------------------
    cvt_bf16_kernel<<<(NN * 256 / 8 + 255) / 256, 256, 0, stream>>>(nf, nfb, NN * 256 / 8);
    cvt_bf16_kernel<<<32, 256, 0, stream>>>(Wq, Wqb, 8192);
    cvt_bf16_kernel<<<32, 256, 0, stream>>>(Wk, Wkb, 8192);
    cvt_bf16_kernel<<<32, 256, 0, stream>>>(Wv, Wvb, 8192);
    cvt_bf16_kernel<<<32, 256, 0, stream>>>(Ws, Wsb, 8192);
    cvt_bf16_kernel<<<24, 256, 0, stream>>>(We, Web, 6144);

    // --- GEMMs -------------------------------------------------------------
    node_gemm_kernel<<<dim3((NN + 127) / 128, 8), 256, 0, stream>>>(
        nfb, Wqb, Wkb, Wvb, Wsb, bq, bk, bv, bs, qb, kb, vb, out);

    edge_gemm_kernel<<<NE / 128, 512, 0, stream>>>(
        tv, w_t, b_t, ef, Web, epb);

    // --- CSR + fused attention/aggregation ---------------------------------
    deg_kernel<<<(NE + 255) / 256, 256, 0, stream>>>(et, deg);
    blocksum_kernel<<<SCAN_NBLK, 256, 0, stream>>>(deg, bsum);
    bscan_kernel<<<1, 256, 0, stream>>>(bsum, rowstart);
    chunkscan_kernel<<<SCAN_NBLK, 256, 0, stream>>>(deg, bsum, rowstart, cursor);
    scatter_kernel<<<(NE + 255) / 256, 256, 0, stream>>>(et, cursor, eslist);

    fused_agg_kernel<<<(NN + 3) / 4, 256, 0, stream>>>(
        eslist, rowstart, qb, kb, vb, epb, out);
}

// Round 10
// 551.447 us; speedup vs baseline: 1.1304x; 1.0500x over previous
//
#include <hip/hip_runtime.h>
#include <hip/hip_bf16.h>
#include <math.h>

#define NN 50000
#define NE 320000
#define SCAN_NBLK ((NN + 255) / 256)   // 196

typedef __attribute__((ext_vector_type(8))) short bf16x8;   // 8 bf16 (4 VGPRs)
typedef __attribute__((ext_vector_type(4))) float floatx4;  // MFMA C/D
typedef __attribute__((ext_vector_type(4))) unsigned int uintx4;  // true vector type
                                                                  // (nontemporal builtin needs it)

static __device__ __forceinline__ unsigned pack2bf(float a, float b) {
    __hip_bfloat162 h = __float22bfloat162_rn(make_float2(a, b));
    return *reinterpret_cast<unsigned*>(&h);
}
static __device__ __forceinline__ unsigned short f2bf(float x) {
    __hip_bfloat16 h = __float2bfloat16(x);
    return *reinterpret_cast<unsigned short*>(&h);
}
static __device__ __forceinline__ float bf2f(unsigned short u) {
    return __uint_as_float(((unsigned)u) << 16);
}
// unpack a uint holding two bf16: low short -> float, high short -> float
static __device__ __forceinline__ float bflo(unsigned u) {
    return __uint_as_float(u << 16);
}
static __device__ __forceinline__ float bfhi(unsigned u) {
    return __uint_as_float(u & 0xffff0000u);
}
// async global->LDS, 16B per lane; lds dest = wave-uniform base + lane*16
static __device__ __forceinline__ void gload_lds16(const void* g, void* l) {
    __builtin_amdgcn_global_load_lds(
        (const __attribute__((address_space(1))) void*)g,
        (__attribute__((address_space(3))) void*)l, 16, 0, 0);
}

// ---------------------------------------------------------------------------
// fp32 -> bf16 streaming convert, 8 elems/thread. n8 = n/8.
// ---------------------------------------------------------------------------
__global__ __launch_bounds__(256)
void cvt_bf16_kernel(const float* __restrict__ in,
                     unsigned short* __restrict__ out, int n8)
{
    int t = blockIdx.x * 256 + threadIdx.x;
    if (t >= n8) return;
    const float4* p = (const float4*)in + (size_t)t * 2;
    float4 a = p[0], b = p[1];
    uint4 u;
    u.x = pack2bf(a.x, a.y); u.y = pack2bf(a.z, a.w);
    u.z = pack2bf(b.x, b.y); u.w = pack2bf(b.z, b.w);
    ((uint4*)out)[t] = u;
}

// ---------------------------------------------------------------------------
// Node projections, pure-bf16 MFMA GEMM with global_load_lds staging.
// C = Xb @ Wb^T (+bias). blockIdx.y = ct: mat = ct>>1, half = ct&1.
// 128x128 tile, BK=64, 4 waves 2x2, 4x4 16x16x32 frags, 2 k-steps per stage.
// ---------------------------------------------------------------------------
__global__ __launch_bounds__(256)
void node_gemm_kernel(const unsigned short* __restrict__ Xb,
                      const unsigned short* __restrict__ Wqb,
                      const unsigned short* __restrict__ Wkb,
                      const unsigned short* __restrict__ Wvb,
                      const unsigned short* __restrict__ Wsb,
                      const float* __restrict__ bq, const float* __restrict__ bk,
                      const float* __restrict__ bv, const float* __restrict__ bs,
                      unsigned short* __restrict__ qb,
                      unsigned short* __restrict__ kb,
                      unsigned short* __restrict__ vb,
                      float* __restrict__ outS)
{
    const int m0  = blockIdx.x * 128;
    const int ct  = blockIdx.y;
    const int mat = ct >> 1, half = ct & 1;
    const int colbase = half * 128;

    const unsigned short* __restrict__ W;
    const float* __restrict__ bias;
    switch (mat) {
        case 0:  W = Wqb; bias = bq; break;
        case 1:  W = Wkb; bias = bk; break;
        case 2:  W = Wvb; bias = bv; break;
        default: W = Wsb; bias = bs; break;
    }
    W += (size_t)colbase * 256;

    __shared__ __align__(16) unsigned char smem[32768];
    short* sA = (short*)smem;             // [128][64]
    short* sB = (short*)(smem + 16384);   // [128][64]

    const int tid  = threadIdx.x;
    const int lane = tid & 63;
    const int wave = tid >> 6;
    const int wm   = (wave & 1) * 64;
    const int wn   = (wave >> 1) * 64;
    const int lr   = lane & 15;
    const int lq   = lane >> 4;

    // staging address pieces: 8 lanes/row, 16B/lane
    const int srow = tid >> 3;            // 0..31 (row within 32-row pass)
    const int scol = (tid & 7) * 8;       // short offset within 64-col slice

    floatx4 acc[4][4];
    #pragma unroll
    for (int i = 0; i < 4; ++i)
        #pragma unroll
        for (int j = 0; j < 4; ++j)
            acc[i][j] = (floatx4){0.f, 0.f, 0.f, 0.f};

    for (int k0 = 0; k0 < 256; k0 += 64) {
        #pragma unroll
        for (int p = 0; p < 4; ++p) {
            int arow = m0 + p * 32 + srow;
            if (arow > NN - 1) arow = NN - 1;             // clamp, masked later
            gload_lds16(Xb + (size_t)arow * 256 + k0 + scol,
                        (char*)sA + p * 4096 + wave * 1024);
            gload_lds16(W + (size_t)(p * 32 + srow) * 256 + k0 + scol,
                        (char*)sB + p * 4096 + wave * 1024);
        }
        __syncthreads();

        #pragma unroll
        for (int ks = 0; ks < 2; ++ks) {
            bf16x8 af[4], bfr[4];
            #pragma unroll
            for (int i = 0; i < 4; ++i)
                af[i] = *(const bf16x8*)&sA[(wm + i * 16 + lr) * 64 + ks * 32 + lq * 8];
            #pragma unroll
            for (int j = 0; j < 4; ++j)
                bfr[j] = *(const bf16x8*)&sB[(wn + j * 16 + lr) * 64 + ks * 32 + lq * 8];
            #pragma unroll
            for (int i = 0; i < 4; ++i)
                #pragma unroll
                for (int j = 0; j < 4; ++j)
                    acc[i][j] = __builtin_amdgcn_mfma_f32_16x16x32_bf16(
                        af[i], bfr[j], acc[i][j], 0, 0, 0);
        }
        __syncthreads();
    }

    if (mat < 3) {
        unsigned short* __restrict__ Cb = (mat == 0) ? qb : (mat == 1) ? kb : vb;
        unsigned short* sOut = (unsigned short*)smem;   // [32][136]
        for (int ch = 0; ch < 4; ++ch) {
            __syncthreads();
            if ((ch >> 1) == (wave & 1)) {
                int ibase = (ch & 1) * 2;
                #pragma unroll
                for (int ii = 0; ii < 2; ++ii) {
                    int i = ibase + ii;
                    #pragma unroll
                    for (int j = 0; j < 4; ++j) {
                        int col = wn + j * 16 + lr;
                        float bb = bias[colbase + col];
                        #pragma unroll
                        for (int r = 0; r < 4; ++r) {
                            int rowc = ii * 16 + lq * 4 + r;
                            sOut[rowc * 136 + col] = f2bf(acc[i][j][r] + bb);
                        }
                    }
                }
            }
            __syncthreads();
            #pragma unroll
            for (int p = 0; p < 2; ++p) {
                int rowc = p * 16 + (tid >> 4);
                int off  = (tid & 15) * 8;
                int grow = m0 + ch * 32 + rowc;
                if (grow < NN) {
                    uint4 u = *(const uint4*)&sOut[rowc * 136 + off];
                    *(uint4*)&Cb[(size_t)grow * 256 + colbase + off] = u;
                }
            }
        }
    } else {
        float* sOutF = (float*)smem;    // [16][132]
        for (int ch = 0; ch < 8; ++ch) {
            __syncthreads();
            if ((ch >> 2) == (wave & 1)) {
                int i = ch & 3;
                #pragma unroll
                for (int j = 0; j < 4; ++j) {
                    int col = wn + j * 16 + lr;
                    float bb = bias[colbase + col];
                    #pragma unroll
                    for (int r = 0; r < 4; ++r) {
                        int rowc = lq * 4 + r;
                        sOutF[rowc * 132 + col] = acc[i][j][r] + bb;
                    }
                }
            }
            __syncthreads();
            #pragma unroll
            for (int p = 0; p < 2; ++p) {
                int rowc = p * 8 + (tid >> 5);
                int off  = (tid & 31) * 4;
                int grow = m0 + ch * 16 + rowc;
                if (grow < NN) {
                    float4 f = *(const float4*)&sOutF[rowc * 132 + off];
                    *(float4*)&outS[(size_t)grow * 256 + colbase + off] = f;
                }
            }
        }
    }
}

// ---------------------------------------------------------------------------
// Edge projection GEMM, 128x256 output per block (8 waves, 512 thr),
// CSR-ORDERED: block row r computes edge elist[m0+r]; epb written at CSR
// position (contiguous) so fused_agg reads epb sequentially.
// A-staging software-pipelined: ef float4 loads for slice t+1 issued one
// phase early (latency hides under cos-build / MFMA of slice t).
// All LDS writes linear base+tid*16 (bank-sequential).
// ---------------------------------------------------------------------------
__global__ __launch_bounds__(512)
void edge_gemm_kernel(const float* __restrict__ tvals,
                      const float* __restrict__ w_time,
                      const float* __restrict__ b_time,
                      const float* __restrict__ ef,
                      const unsigned short* __restrict__ Web,
                      const int* __restrict__ elist,
                      unsigned short* __restrict__ epb)
{
    const int m0 = blockIdx.x * 128;

    __shared__ __align__(16) unsigned char smem[49152];
    short* sA = (short*)smem;             // [128][64] linear
    short* sB = (short*)(smem + 16384);   // [256][64] linear

    const int tid  = threadIdx.x;         // 0..511
    const int lane = tid & 63;
    const int wave = tid >> 6;            // 0..7
    const int wm   = (wave & 1) * 64;
    const int wn   = (wave >> 1) * 64;
    const int lr   = lane & 15;
    const int lq   = lane >> 4;
    const int c8   = (tid & 7) * 8;       // col offset within 64-col slice

    // CSR gather indices for my two A rows
    const int e0 = elist[m0 + (tid >> 3)];
    const int e1 = elist[m0 + 64 + (tid >> 3)];
    const float* __restrict__ efr0 = ef + (size_t)e0 * 128 + c8;
    const float* __restrict__ efr1 = ef + (size_t)e1 * 128 + c8;

    floatx4 acc[4][4];
    #pragma unroll
    for (int i = 0; i < 4; ++i)
        #pragma unroll
        for (int j = 0; j < 4; ++j)
            acc[i][j] = (floatx4){0.f, 0.f, 0.f, 0.f};

    // ---- prefetch ef slice k=64 (issued before any barrier) ----
    float4 f0 = ((const float4*)efr0)[0];
    float4 f1 = ((const float4*)efr0)[1];
    float4 f2 = ((const float4*)efr1)[0];
    float4 f3 = ((const float4*)efr1)[1];

    // ================= phase 0: k0 = 0 (time encoder) =================
    #pragma unroll
    for (int p = 0; p < 4; ++p)
        gload_lds16(Web + (size_t)(p * 64 + (tid >> 3)) * 192 + 0 + c8,
                    (char*)sB + p * 8192 + wave * 1024);
    {
        float4 w0 = *(const float4*)(w_time + c8);
        float4 w1 = *(const float4*)(w_time + c8 + 4);
        float4 b0 = *(const float4*)(b_time + c8);
        float4 b1 = *(const float4*)(b_time + c8 + 4);
        float tv0 = tvals[e0], tv1 = tvals[e1];
        uint4 u;
        u.x = pack2bf(cosf(fmaf(tv0, w0.x, b0.x)), cosf(fmaf(tv0, w0.y, b0.y)));
        u.y = pack2bf(cosf(fmaf(tv0, w0.z, b0.z)), cosf(fmaf(tv0, w0.w, b0.w)));
        u.z = pack2bf(cosf(fmaf(tv0, w1.x, b1.x)), cosf(fmaf(tv0, w1.y, b1.y)));
        u.w = pack2bf(cosf(fmaf(tv0, w1.z, b1.z)), cosf(fmaf(tv0, w1.w, b1.w)));
        *(uint4*)&sA[tid * 8] = u;
        u.x = pack2bf(cosf(fmaf(tv1, w0.x, b0.x)), cosf(fmaf(tv1, w0.y, b0.y)));
        u.y = pack2bf(cosf(fmaf(tv1, w0.z, b0.z)), cosf(fmaf(tv1, w0.w, b0.w)));
        u.z = pack2bf(cosf(fmaf(tv1, w1.x, b1.x)), cosf(fmaf(tv1, w1.y, b1.y)));
        u.w = pack2bf(cosf(fmaf(tv1, w1.z, b1.z)), cosf(fmaf(tv1, w1.w, b1.w)));
        *(uint4*)&sA[4096 + tid * 8] = u;
    }
    __syncthreads();
    #pragma unroll
    for (int ks = 0; ks < 2; ++ks) {
        bf16x8 af[4], bfr[4];
        #pragma unroll
        for (int i = 0; i < 4; ++i)
            af[i] = *(const bf16x8*)&sA[(wm + i * 16 + lr) * 64 + ks * 32 + lq * 8];
        #pragma unroll
        for (int j = 0; j < 4; ++j)
            bfr[j] = *(const bf16x8*)&sB[(wn + j * 16 + lr) * 64 + ks * 32 + lq * 8];
        #pragma unroll
        for (int i = 0; i < 4; ++i)
            #pragma unroll
            for (int j = 0; j < 4; ++j)
                acc[i][j] = __builtin_amdgcn_mfma_f32_16x16x32_bf16(
                    af[i], bfr[j], acc[i][j], 0, 0, 0);
    }
    __syncthreads();

    // ================= phase 1: k0 = 64 (ef cols 0..63) =================
    {
        uint4 u;
        u.x = pack2bf(f0.x, f0.y); u.y = pack2bf(f0.z, f0.w);
        u.z = pack2bf(f1.x, f1.y); u.w = pack2bf(f1.z, f1.w);
        *(uint4*)&sA[tid * 8] = u;
        u.x = pack2bf(f2.x, f2.y); u.y = pack2bf(f2.z, f2.w);
        u.z = pack2bf(f3.x, f3.y); u.w = pack2bf(f3.z, f3.w);
        *(uint4*)&sA[4096 + tid * 8] = u;
    }
    // prefetch ef slice k=128 (cols 64..127)
    f0 = ((const float4*)(efr0 + 64))[0];
    f1 = ((const float4*)(efr0 + 64))[1];
    f2 = ((const float4*)(efr1 + 64))[0];
    f3 = ((const float4*)(efr1 + 64))[1];
    #pragma unroll
    for (int p = 0; p < 4; ++p)
        gload_lds16(Web + (size_t)(p * 64 + (tid >> 3)) * 192 + 64 + c8,
                    (char*)sB + p * 8192 + wave * 1024);
    __syncthreads();
    #pragma unroll
    for (int ks = 0; ks < 2; ++ks) {
        bf16x8 af[4], bfr[4];
        #pragma unroll
        for (int i = 0; i < 4; ++i)
            af[i] = *(const bf16x8*)&sA[(wm + i * 16 + lr) * 64 + ks * 32 + lq * 8];
        #pragma unroll
        for (int j = 0; j < 4; ++j)
            bfr[j] = *(const bf16x8*)&sB[(wn + j * 16 + lr) * 64 + ks * 32 + lq * 8];
        #pragma unroll
        for (int i = 0; i < 4; ++i)
            #pragma unroll
            for (int j = 0; j < 4; ++j)
                acc[i][j] = __builtin_amdgcn_mfma_f32_16x16x32_bf16(
                    af[i], bfr[j], acc[i][j], 0, 0, 0);
    }
    __syncthreads();

    // ================= phase 2: k0 = 128 (ef cols 64..127) =================
    {
        uint4 u;
        u.x = pack2bf(f0.x, f0.y); u.y = pack2bf(f0.z, f0.w);
        u.z = pack2bf(f1.x, f1.y); u.w = pack2bf(f1.z, f1.w);
        *(uint4*)&sA[tid * 8] = u;
        u.x = pack2bf(f2.x, f2.y); u.y = pack2bf(f2.z, f2.w);
        u.z = pack2bf(f3.x, f3.y); u.w = pack2bf(f3.z, f3.w);
        *(uint4*)&sA[4096 + tid * 8] = u;
    }
    #pragma unroll
    for (int p = 0; p < 4; ++p)
        gload_lds16(Web + (size_t)(p * 64 + (tid >> 3)) * 192 + 128 + c8,
                    (char*)sB + p * 8192 + wave * 1024);
    __syncthreads();
    #pragma unroll
    for (int ks = 0; ks < 2; ++ks) {
        bf16x8 af[4], bfr[4];
        #pragma unroll
        for (int i = 0; i < 4; ++i)
            af[i] = *(const bf16x8*)&sA[(wm + i * 16 + lr) * 64 + ks * 32 + lq * 8];
        #pragma unroll
        for (int j = 0; j < 4; ++j)
            bfr[j] = *(const bf16x8*)&sB[(wn + j * 16 + lr) * 64 + ks * 32 + lq * 8];
        #pragma unroll
        for (int i = 0; i < 4; ++i)
            #pragma unroll
            for (int j = 0; j < 4; ++j)
                acc[i][j] = __builtin_amdgcn_mfma_f32_16x16x32_bf16(
                    af[i], bfr[j], acc[i][j], 0, 0, 0);
    }
    __syncthreads();

    // epilogue: 4 chunks of 32 rows x 256 cols via LDS bounce [32][264]
    unsigned short* sOut = (unsigned short*)smem;
    for (int ch = 0; ch < 4; ++ch) {
        __syncthreads();
        if ((wave & 1) == (ch >> 1)) {
            int ibase = (ch & 1) * 2;
            #pragma unroll
            for (int ii = 0; ii < 2; ++ii) {
                int i = ibase + ii;
                #pragma unroll
                for (int j = 0; j < 4; ++j) {
                    int col = wn + j * 16 + lr;
                    #pragma unroll
                    for (int r = 0; r < 4; ++r) {
                        int rowc = ii * 16 + lq * 4 + r;
                        sOut[rowc * 264 + col] = f2bf(acc[i][j][r]);
                    }
                }
            }
        }
        __syncthreads();
        #pragma unroll
        for (int p = 0; p < 2; ++p) {
            int rl   = p * 16 + (tid >> 5);
            int off  = (tid & 31) * 8;
            int grow = m0 + ch * 32 + rl;      // CSR position (contiguous)
            uint4 u = *(const uint4*)&sOut[rl * 264 + off];
            *(uint4*)&epb[(size_t)grow * 256 + off] = u;
        }
    }
}

// ---------------------------------------------------------------------------
// CSR build: histogram, 3-phase parallel scan, scatter (elist + slist).
// ---------------------------------------------------------------------------
__global__ __launch_bounds__(256)
void deg_kernel(const int* __restrict__ et, int* __restrict__ deg)
{
    int e = blockIdx.x * 256 + threadIdx.x;
    if (e < NE) atomicAdd(&deg[et[NE + e]], 1);
}

// Phase A: per-block (256-node chunk) sums -> bsum[SCAN_NBLK]
__global__ __launch_bounds__(256)
void blocksum_kernel(const int* __restrict__ deg, int* __restrict__ bsum)
{
    int idx = blockIdx.x * 256 + threadIdx.x;
    int v = (idx < NN) ? deg[idx] : 0;
    #pragma unroll
    for (int off = 1; off < 64; off <<= 1) v += __shfl_xor(v, off);
    __shared__ int s[4];
    if ((threadIdx.x & 63) == 0) s[threadIdx.x >> 6] = v;
    __syncthreads();
    if (threadIdx.x == 0) bsum[blockIdx.x] = s[0] + s[1] + s[2] + s[3];
}

// Phase B: single small block exclusive-scans bsum in place; writes total.
__global__ __launch_bounds__(256)
void bscan_kernel(int* __restrict__ bsum, int* __restrict__ rowstart)
{
    __shared__ int s[256];
    int t = threadIdx.x;
    int v = (t < SCAN_NBLK) ? bsum[t] : 0;
    s[t] = v;
    __syncthreads();
    #pragma unroll
    for (int off = 1; off < 256; off <<= 1) {
        int u = (t >= off) ? s[t - off] : 0;
        __syncthreads();
        s[t] += u;
        __syncthreads();
    }
    if (t < SCAN_NBLK) bsum[t] = (t == 0) ? 0 : s[t - 1];   // exclusive
    if (t == 0) rowstart[NN] = s[SCAN_NBLK - 1];            // total = NE
}

// Phase C: per-chunk exclusive scan + block offset -> rowstart, cursor.
__global__ __launch_bounds__(256)
void chunkscan_kernel(const int* __restrict__ deg, const int* __restrict__ bsum,
                      int* __restrict__ rowstart, int* __restrict__ cursor)
{
    __shared__ int s[256];
    int t = threadIdx.x;
    int idx = blockIdx.x * 256 + t;
    int v = (idx < NN) ? deg[idx] : 0;
    s[t] = v;
    __syncthreads();
    #pragma unroll
    for (int off = 1; off < 256; off <<= 1) {
        int u = (t >= off) ? s[t - off] : 0;
        __syncthreads();
        s[t] += u;
        __syncthreads();
    }
    if (idx < NN) {
        int ex = bsum[blockIdx.x] + s[t] - v;   // exclusive within-chunk + offset
        rowstart[idx] = ex;
        cursor[idx]   = ex;
    }
}

__global__ __launch_bounds__(256)
void scatter_kernel(const int* __restrict__ et,
                    int* __restrict__ cursor,
                    int* __restrict__ elist, int* __restrict__ slist)
{
    int e = blockIdx.x * 256 + threadIdx.x;
    if (e < NE) {
        int d   = et[NE + e];
        int pos = atomicAdd(&cursor[d], 1);
        elist[pos] = e;
        slist[pos] = et[e];
    }
}

// ---------------------------------------------------------------------------
// Fused attention + aggregation + skip. epb is CSR-ordered: position-indexed
// SEQUENTIAL reads (nontemporal stream). Indices: one broadcast 4B slist
// load per edge. Lane-half h = edge i+h; lane covers 8 ch (16B gathers);
// x2 pair unroll = 4 edges in flight; shfl_xor(32) combine.
// ---------------------------------------------------------------------------
static __device__ __forceinline__ void edge_proc(
    uint4 ku, uint4 vu, uintx4 eu, const float* q, float mask,
    float* a, float& accd)
{
    float pe0 = bflo(eu[0]), pe1 = bfhi(eu[0]);
    float pe2 = bflo(eu[1]), pe3 = bfhi(eu[1]);
    float pe4 = bflo(eu[2]), pe5 = bfhi(eu[2]);
    float pe6 = bflo(eu[3]), pe7 = bfhi(eu[3]);

    float part;
    part = q[0] * (bflo(ku.x) + pe0);
    part = fmaf(q[1], bfhi(ku.x) + pe1, part);
    part = fmaf(q[2], bflo(ku.y) + pe2, part);
    part = fmaf(q[3], bfhi(ku.y) + pe3, part);
    part = fmaf(q[4], bflo(ku.z) + pe4, part);
    part = fmaf(q[5], bfhi(ku.z) + pe5, part);
    part = fmaf(q[6], bflo(ku.w) + pe6, part);
    part = fmaf(q[7], bfhi(ku.w) + pe7, part);
    part += __shfl_xor(part, 1);
    part += __shfl_xor(part, 2);

    float ea = __expf(part * 0.17677669529663687f) * mask;  // 1/sqrt(32)

    a[0] = fmaf(ea, bflo(vu.x) + pe0, a[0]);
    a[1] = fmaf(ea, bfhi(vu.x) + pe1, a[1]);
    a[2] = fmaf(ea, bflo(vu.y) + pe2, a[2]);
    a[3] = fmaf(ea, bfhi(vu.y) + pe3, a[3]);
    a[4] = fmaf(ea, bflo(vu.z) + pe4, a[4]);
    a[5] = fmaf(ea, bfhi(vu.z) + pe5, a[5]);
    a[6] = fmaf(ea, bflo(vu.w) + pe6, a[6]);
    a[7] = fmaf(ea, bfhi(vu.w) + pe7, a[7]);
    accd += ea;
}

__global__ __launch_bounds__(256)
void fused_agg_kernel(const int* __restrict__ slist,
                      const int* __restrict__ rowstart,
                      const unsigned short* __restrict__ qb,
                      const unsigned short* __restrict__ kb,
                      const unsigned short* __restrict__ vb,
                      const unsigned short* __restrict__ epb,
                      float* __restrict__ out)
{
    const int n = blockIdx.x * 4 + (threadIdx.x >> 6);
    if (n >= NN) return;
    const int lane = threadIdx.x & 63;
    const int half = lane >> 5;         // 0: edge i, 1: edge i+1
    const int co   = (lane & 31) * 8;   // my 8 channels

    uint4 qu = *(const uint4*)(qb + (size_t)n * 256 + co);
    float q[8] = { bflo(qu.x), bfhi(qu.x), bflo(qu.y), bfhi(qu.y),
                   bflo(qu.z), bfhi(qu.z), bflo(qu.w), bfhi(qu.w) };

    float a[8] = {0.f, 0.f, 0.f, 0.f, 0.f, 0.f, 0.f, 0.f};
    float accd = 0.f;

    const int s0 = rowstart[n];
    const int s1 = rowstart[n + 1];

    int i = s0;
    for (; i + 4 <= s1; i += 4) {
        const int iA = i + half, iB = i + 2 + half;
        const int srcA = slist[iA];
        const int srcB = slist[iB];
        uint4 kA = *(const uint4*)(kb + (size_t)srcA * 256 + co);
        uint4 vA = *(const uint4*)(vb + (size_t)srcA * 256 + co);
        uintx4 eA = __builtin_nontemporal_load(
                        (const uintx4*)(epb + (size_t)iA * 256 + co));
        uint4 kB = *(const uint4*)(kb + (size_t)srcB * 256 + co);
        uint4 vB = *(const uint4*)(vb + (size_t)srcB * 256 + co);
        uintx4 eB = __builtin_nontemporal_load(
                        (const uintx4*)(epb + (size_t)iB * 256 + co));

        edge_proc(kA, vA, eA, q, 1.f, a, accd);
        edge_proc(kB, vB, eB, q, 1.f, a, accd);
    }
    for (; i + 2 <= s1; i += 2) {
        const int iA = i + half;
        const int srcA = slist[iA];
        uint4 kA = *(const uint4*)(kb + (size_t)srcA * 256 + co);
        uint4 vA = *(const uint4*)(vb + (size_t)srcA * 256 + co);
        uintx4 eA = __builtin_nontemporal_load(
                        (const uintx4*)(epb + (size_t)iA * 256 + co));
        edge_proc(kA, vA, eA, q, 1.f, a, accd);
    }
    if (i < s1) {
        // masked pair: hi half loads the same edge but contributes 0
        int idx = i + half;
        float mask = (idx < s1) ? 1.f : 0.f;
        if (idx >= s1) idx = s1 - 1;
        const int srcA = slist[idx];
        uint4 kA = *(const uint4*)(kb + (size_t)srcA * 256 + co);
        uint4 vA = *(const uint4*)(vb + (size_t)srcA * 256 + co);
        uintx4 eA = __builtin_nontemporal_load(
                        (const uintx4*)(epb + (size_t)idx * 256 + co));
        edge_proc(kA, vA, eA, q, mask, a, accd);
    }

    // combine lane-halves (same channels, same head in both halves)
    #pragma unroll
    for (int j = 0; j < 8; ++j) a[j] += __shfl_xor(a[j], 32);
    accd += __shfl_xor(accd, 32);

    if (half == 0) {
        const float inv = 1.f / (accd + 1e-16f);
        float* po = out + (size_t)n * 256 + co;
        float4 o0 = ((const float4*)po)[0];
        float4 o1 = ((const float4*)po)[1];
        o0.x = fmaf(a[0], inv, o0.x);
        o0.y = fmaf(a[1], inv, o0.y);
        o0.z = fmaf(a[2], inv, o0.z);
        o0.w = fmaf(a[3], inv, o0.w);
        o1.x = fmaf(a[4], inv, o1.x);
        o1.y = fmaf(a[5], inv, o1.y);
        o1.z = fmaf(a[6], inv, o1.z);
        o1.w = fmaf(a[7], inv, o1.w);
        ((float4*)po)[0] = o0;
        ((float4*)po)[1] = o1;
    }
}

// ---------------------------------------------------------------------------
extern "C" void kernel_launch(void* const* d_in, const int* in_sizes, int n_in,
                              void* d_out, int out_size, void* d_ws, size_t ws_size,
                              hipStream_t stream)
{
    const int*   et  = (const int*)  d_in[0];
    const float* ef  = (const float*)d_in[1];
    const float* tv  = (const float*)d_in[2];
    const float* nf  = (const float*)d_in[3];
    const float* w_t = (const float*)d_in[4];
    const float* b_t = (const float*)d_in[5];
    const float* Wq  = (const float*)d_in[6];
    const float* bq  = (const float*)d_in[7];
    const float* Wk  = (const float*)d_in[8];
    const float* bk  = (const float*)d_in[9];
    const float* Wv  = (const float*)d_in[10];
    const float* bv  = (const float*)d_in[11];
    const float* We  = (const float*)d_in[12];
    const float* Ws  = (const float*)d_in[13];
    const float* bs  = (const float*)d_in[14];
    float* out = (float*)d_out;

    // ws layout (bf16 buffers then ints)
    unsigned short* qb  = (unsigned short*)d_ws;
    unsigned short* kb  = qb  + (size_t)NN * 256;
    unsigned short* vb  = kb  + (size_t)NN * 256;
    unsigned short* epb = vb  + (size_t)NN * 256;
    unsigned short* nfb = epb + (size_t)NE * 256;
    unsigned short* Wqb = nfb + (size_t)NN * 256;
    unsigned short* Wkb = Wqb + 65536;
    unsigned short* Wvb = Wkb + 65536;
    unsigned short* Wsb = Wvb + 65536;
    unsigned short* Web = Wsb + 65536;
    int* deg      = (int*)(Web + 49152);
    int* rowstart = deg + NN;
    int* cursor   = rowstart + NN + 1;
    int* elist    = cursor + NN;
    int* slist    = elist + NE;
    int* bsum     = slist + NE;
    size_t need   = (size_t)((char*)(bsum + SCAN_NBLK) - (char*)d_ws);
    if (ws_size < need) return;

    (void)hipMemsetAsync(deg, 0, (size_t)NN * sizeof(int), stream);

    // --- CSR build first (edge_gemm consumes elist) ------------------------
    deg_kernel<<<(NE + 255) / 256, 256, 0, stream>>>(et, deg);
    blocksum_kernel<<<SCAN_NBLK, 256, 0, stream>>>(deg, bsum);
    bscan_kernel<<<1, 256, 0, stream>>>(bsum, rowstart);
    chunkscan_kernel<<<SCAN_NBLK, 256, 0, stream>>>(deg, bsum, rowstart, cursor);
    scatter_kernel<<<(NE + 255) / 256, 256, 0, stream>>>(et, cursor, elist, slist);

    // --- prep: bf16 conversions -------------------------------------------
    cvt_bf16_kernel<<<(NN * 256 / 8 + 255) / 256, 256, 0, stream>>>(nf, nfb, NN * 256 / 8);
    cvt_bf16_kernel<<<32, 256, 0, stream>>>(Wq, Wqb, 8192);
    cvt_bf16_kernel<<<32, 256, 0, stream>>>(Wk, Wkb, 8192);
    cvt_bf16_kernel<<<32, 256, 0, stream>>>(Wv, Wvb, 8192);
    cvt_bf16_kernel<<<32, 256, 0, stream>>>(Ws, Wsb, 8192);
    cvt_bf16_kernel<<<24, 256, 0, stream>>>(We, Web, 6144);

    // --- GEMMs -------------------------------------------------------------
    node_gemm_kernel<<<dim3((NN + 127) / 128, 8), 256, 0, stream>>>(
        nfb, Wqb, Wkb, Wvb, Wsb, bq, bk, bv, bs, qb, kb, vb, out);

    edge_gemm_kernel<<<NE / 128, 512, 0, stream>>>(
        tv, w_t, b_t, ef, Web, elist, epb);

    // --- fused attention/aggregation ---------------------------------------
    fused_agg_kernel<<<(NN + 3) / 4, 256, 0, stream>>>(
        slist, rowstart, qb, kb, vb, epb, out);
}